// Round 2
// baseline (312.640 us; speedup 1.0000x reference)
//
#include <hip/hip_runtime.h>
#include <hip/hip_bf16.h>
#include <stdint.h>
#include <stddef.h>

// E=8, B=16, T=512, DIN=256, D=256; M = B*T = 8192 rows per ensemble member.
// Stage1: u = x @ W_in[m], v=tanh(u0), f=sig(u1)*(1-rs)  -> scan1 -> v4
// Stage2: u = v4 @ W_mid[m], gates f,i,o,z               -> scan2 -> g = h*o
// Stage3: out = g @ W_out + b_out
// GEMMs: bf16 MFMA 16x16x32, f32 accum, double-buffered LDS w/ counted vmcnt,
// swapped-operand epilogue (C^T fragment => 4 consecutive d per lane).

typedef __bf16 bf16x8 __attribute__((ext_vector_type(8)));
typedef __bf16 bf16x4 __attribute__((ext_vector_type(4)));
typedef float  f32x4  __attribute__((ext_vector_type(4)));
typedef unsigned int u32x2 __attribute__((ext_vector_type(2)));

#define E_ 8
#define M_ 8192
#define K_ 256

__device__ __forceinline__ float sigm_f(float x) { return 1.0f / (1.0f + __expf(-x)); }
__device__ __forceinline__ float tanh_f(float x) { return 1.0f - 2.0f / (1.0f + __expf(2.0f * x)); }

__device__ __forceinline__ void g2lds16(const void* g, void* l) {
    __builtin_amdgcn_global_load_lds((const __attribute__((address_space(1))) void*)g,
                                     (__attribute__((address_space(3))) void*)l, 16, 0, 0);
}

// ---------------- convert x to bf16 ----------------
__global__ __launch_bounds__(256) void convx_k(const float* __restrict__ x, __bf16* __restrict__ xb) {
    int i = blockIdx.x * 256 + threadIdx.x;
    float4 v = ((const float4*)x)[i];
    bf16x4 o;
    o[0] = (__bf16)v.x; o[1] = (__bf16)v.y; o[2] = (__bf16)v.z; o[3] = (__bf16)v.w;
    ((bf16x4*)xb)[i] = o;
}

// ---------------- transpose+convert weights: src [GE][K][D] f32 -> dst [E][NG*256][K] bf16 ----
__global__ __launch_bounds__(256) void transw_k(const float* __restrict__ src, __bf16* __restrict__ dst, int NG) {
    int ge = blockIdx.z;
    int g = ge >> 3, e = ge & 7;
    int k0 = blockIdx.x * 64, d0 = blockIdx.y * 64;
    __shared__ float tile[64][65];
    int t = threadIdx.x;
#pragma unroll
    for (int j = 0; j < 16; ++j) {
        int lin = j * 256 + t;
        int r = lin >> 6, c = lin & 63;
        tile[r][c] = src[((size_t)(ge * 256 + k0 + r)) * 256 + d0 + c];
    }
    __syncthreads();
#pragma unroll
    for (int j = 0; j < 16; ++j) {
        int lin = j * 256 + t;
        int r = lin >> 6, c = lin & 63;
        dst[((size_t)((e * NG + g) * 256 + d0 + r)) * 256 + k0 + c] = (__bf16)tile[c][r];
    }
}

// ---------------- GEMM: A [E][M][K] bf16 x Wt [E][NG*256][K] bf16 -----------
// MODE 0: stage1 (NG=2: g0 tanh, g1 sig*(1-rs))  bf16 slabs [NG][E][M][D]
// MODE 1: stage2 (NG=4: g0 sig*(1-rs), g1 sig, g2 sig, g3 tanh)
// MODE 2: stage3 (NG=1: linear + bias, f32 -> d_out)
template <int MODE, int NG>
__global__ __launch_bounds__(256, 2) void gemm_k(const __bf16* __restrict__ A,
                                                 const __bf16* __restrict__ Wt,
                                                 const float* __restrict__ bias,
                                                 const float* __restrict__ rs,
                                                 __bf16* __restrict__ gout,
                                                 float* __restrict__ fout) {
    constexpr int NT = NG * 2;                 // N-tiles of 128 over NG*256 cols
    const int tid = threadIdx.x;
    // XCD-aware swizzle: each XCD owns one contiguous chunk (= one ensemble e)
    int lin = blockIdx.x;
    int swz = (lin & 7) * (NT * 64) + (lin >> 3);
    const int nt = swz % NT;
    const int mt = (swz / NT) & 63;
    const int e  = swz / (NT * 64);
    const int m0 = mt * 128;
    const int lane = tid & 63, wid = tid >> 6;
    const int wr = wid >> 1, wc = wid & 1;

    __shared__ __align__(16) __bf16 As[2][8192];  // 128 rows x 64 k, XOR-swizzled 16B granules
    __shared__ __align__(16) __bf16 Bs[2][8192];

    const size_t Abase = ((size_t)e * M_ + m0) * K_;
    const size_t Bbase = ((size_t)e * (NG * 256) + nt * 128) * K_;

    f32x4 acc[4][4] = {};

    auto stage = [&](int kt, int buf) {        // 8 vmem instrs / wave
#pragma unroll
        for (int r = 0; r < 4; ++r) {
            int P = r * 256 + tid;             // 16B-granule index
            int row = P >> 3, gl = P & 7;
            int gs = gl ^ (row & 7);           // pre-swizzled global source, linear LDS dest
            g2lds16(A + Abase + (size_t)row * K_ + kt * 64 + gs * 8, &As[buf][P * 8]);
            g2lds16(Wt + Bbase + (size_t)row * K_ + kt * 64 + gs * 8, &Bs[buf][P * 8]);
        }
    };

    stage(0, 0);
    int buf = 0;
#pragma unroll
    for (int kt = 0; kt < 4; ++kt) {
        if (kt < 3) {
            stage(kt + 1, buf ^ 1);
            asm volatile("s_waitcnt vmcnt(8)" ::: "memory");   // current tile done, next in flight
        } else {
            asm volatile("s_waitcnt vmcnt(0)" ::: "memory");
        }
        __builtin_amdgcn_s_barrier();
#pragma unroll
        for (int ks = 0; ks < 2; ++ks) {
            bf16x8 af[4], bfr[4];
#pragma unroll
            for (int i = 0; i < 4; ++i) {
                int ar = wr * 64 + i * 16 + (lane & 15);
                int ag = (ks * 4 + (lane >> 4)) ^ (ar & 7);
                af[i] = *(const bf16x8*)&As[buf][ar * 64 + ag * 8];
                int bc = wc * 64 + i * 16 + (lane & 15);
                int bg = (ks * 4 + (lane >> 4)) ^ (bc & 7);
                bfr[i] = *(const bf16x8*)&Bs[buf][bc * 64 + bg * 8];
            }
#pragma unroll
            for (int i = 0; i < 4; ++i)
#pragma unroll
                for (int j = 0; j < 4; ++j)
                    // swapped operands: acc[i][j] = (A.B)^T fragment
                    acc[i][j] = __builtin_amdgcn_mfma_f32_16x16x32_bf16(bfr[j], af[i], acc[i][j], 0, 0, 0);
        }
        asm volatile("s_waitcnt lgkmcnt(0)" ::: "memory");     // ds_reads complete before reuse
        __builtin_amdgcn_s_barrier();
        __builtin_amdgcn_sched_barrier(0);
        buf ^= 1;
    }

    // epilogue: C^T fragment => lane holds m = i*16+(lane&15) fixed,
    // 4 consecutive d = j*16 + (lane>>4)*4 + q  -> vector stores
    const int mlo = m0 + wr * 64 + (lane & 15);
    float rsv[4];
    if (MODE != 2) {
#pragma unroll
        for (int i = 0; i < 4; ++i) rsv[i] = 1.0f - rs[mlo + i * 16];
    }
#pragma unroll
    for (int j = 0; j < 4; ++j) {
        int nb = nt * 128 + wc * 64 + j * 16 + ((lane >> 4) << 2);
        int g = nb >> 8, d = nb & 255;
        f32x4 bv = *(const f32x4*)&bias[(g * E_ + e) * 256 + d];
#pragma unroll
        for (int i = 0; i < 4; ++i) {
            int m = mlo + i * 16;
            if (MODE == 2) {
                f32x4 o = acc[i][j] + bv;
                __builtin_nontemporal_store(o, (f32x4*)&fout[((size_t)e * M_ + m) * 256 + d]);
            } else {
                bf16x4 pk;
#pragma unroll
                for (int q = 0; q < 4; ++q) {
                    float u = acc[i][j][q] + bv[q];
                    bool is_tanh = (MODE == 0) ? (g == 0) : (g == 3);
                    bool gated   = (MODE == 0) ? (g == 1) : (g == 0);
                    float a = is_tanh ? tanh_f(u) : sigm_f(u);
                    if (gated) a *= rsv[i];
                    pk[q] = (__bf16)a;
                }
                u32x2 pv = __builtin_bit_cast(u32x2, pk);
                __builtin_nontemporal_store(pv, (u32x2*)&gout[(((size_t)g * E_ + e) * M_ + m) * 256 + d]);
            }
        }
    }
}

// ---------------- scan 1: h = f*h + (1-f)*v  (thread per (n,d), 2 waves/CU) ----
__global__ __launch_bounds__(256) void scan1_k(const __bf16* __restrict__ V, const __bf16* __restrict__ F,
                                               const float* __restrict__ hidden,
                                               __bf16* __restrict__ v4b, float* __restrict__ hidout) {
    int gid = blockIdx.x * 256 + threadIdx.x;   // 0..32767
    int n = gid >> 8, d = gid & 255;
    float h = hidden[n * 512 + d];
    size_t base = (size_t)n * 512 * 256 + d;
#pragma unroll 1
    for (int tb = 0; tb < 512; tb += 16) {
        float fv[16], bv[16];
#pragma unroll
        for (int u = 0; u < 16; ++u) {
            size_t idx = base + (size_t)(tb + u) * 256;
            float f = (float)F[idx];
            float v = (float)V[idx];
            fv[u] = f; bv[u] = (1.0f - f) * v;  // off the recurrence chain
        }
#pragma unroll
        for (int u = 0; u < 16; ++u) {
            h = __builtin_fmaf(fv[u], h, bv[u]);
            v4b[base + (size_t)(tb + u) * 256] = (__bf16)h;
        }
    }
    hidout[n * 512 + d] = h;
}

// ---------------- scan 2: h = f*h + (1-f)*(i*z); out = h*o ----
__global__ __launch_bounds__(256) void scan2_k(const __bf16* __restrict__ Fg, const __bf16* __restrict__ Ig,
                                               const __bf16* __restrict__ Og, const __bf16* __restrict__ Zg,
                                               const float* __restrict__ hidden,
                                               __bf16* __restrict__ G, float* __restrict__ hidout) {
    int gid = blockIdx.x * 256 + threadIdx.x;
    int n = gid >> 8, d = gid & 255;
    float h = hidden[n * 512 + 256 + d];
    size_t base = (size_t)n * 512 * 256 + d;
#pragma unroll 1
    for (int tb = 0; tb < 512; tb += 8) {
        float fv[8], bv[8], ov[8];
#pragma unroll
        for (int u = 0; u < 8; ++u) {
            size_t idx = base + (size_t)(tb + u) * 256;
            float f = (float)Fg[idx], iv = (float)Ig[idx], o = (float)Og[idx], z = (float)Zg[idx];
            fv[u] = f; bv[u] = (1.0f - f) * (iv * z); ov[u] = o;
        }
#pragma unroll
        for (int u = 0; u < 8; ++u) {
            h = __builtin_fmaf(fv[u], h, bv[u]);
            size_t idx = base + (size_t)(tb + u) * 256;
            G[idx] = (__bf16)(h * ov[u]);
        }
    }
    hidout[n * 512 + 256 + d] = h;
}

extern "C" void kernel_launch(void* const* d_in, const int* in_sizes, int n_in,
                              void* d_out, int out_size, void* d_ws, size_t ws_size,
                              hipStream_t stream) {
    const float* x      = (const float*)d_in[0];
    const float* hidden = (const float*)d_in[1];
    const float* rs     = (const float*)d_in[2];
    const float* W_in   = (const float*)d_in[3];
    const float* b_in   = (const float*)d_in[4];
    const float* W_mid  = (const float*)d_in[5];
    const float* b_mid  = (const float*)d_in[6];
    const float* W_out  = (const float*)d_in[7];
    const float* b_out  = (const float*)d_in[8];
    float* out = (float*)d_out;

    char* ws = (char*)d_ws;
    const size_t MiB = (size_t)1 << 20;
    __bf16* Wt1 = (__bf16*)(ws + 0);               // 2 MiB
    __bf16* Wt2 = (__bf16*)(ws + 2 * MiB);         // 4 MiB
    __bf16* Wt3 = (__bf16*)(ws + 6 * MiB);         // 1 MiB
    __bf16* v4b = (__bf16*)(ws + 8 * MiB);         // 32 MiB; reused as G after gemm2
    __bf16* xb  = (__bf16*)(ws + 40 * MiB);        // 32 MiB
    __bf16* g1  = (__bf16*)(ws + 72 * MiB);        // 64 MiB  [2][E][M][D]
    __bf16* g2  = (__bf16*)(ws + 40 * MiB);        // 128 MiB [4][E][M][D], overlays xb+g1
    const size_t S1 = (size_t)E_ * M_ * 256;

    float* hidout = out + (size_t)E_ * M_ * 256;

    convx_k<<<16384, 256, 0, stream>>>(x, xb);
    transw_k<<<dim3(4, 4, 16), 256, 0, stream>>>(W_in, Wt1, 2);
    transw_k<<<dim3(4, 4, 32), 256, 0, stream>>>(W_mid, Wt2, 4);
    transw_k<<<dim3(4, 4, 8), 256, 0, stream>>>(W_out, Wt3, 1);

    gemm_k<0, 2><<<2048, 256, 0, stream>>>(xb, Wt1, b_in, rs, g1, nullptr);
    scan1_k<<<128, 256, 0, stream>>>(g1, g1 + S1, hidden, v4b, hidout);
    gemm_k<1, 4><<<4096, 256, 0, stream>>>(v4b, Wt2, b_mid, rs, g2, nullptr);
    scan2_k<<<128, 256, 0, stream>>>(g2, g2 + S1, g2 + 2 * S1, g2 + 3 * S1, hidden, v4b, hidout);
    gemm_k<2, 1><<<1024, 256, 0, stream>>>(v4b, Wt3, b_out, nullptr, nullptr, out);
}

// Round 3
// 279.645 us; speedup vs baseline: 1.1180x; 1.1180x over previous
//
#include <hip/hip_runtime.h>
#include <hip/hip_bf16.h>
#include <stdint.h>
#include <stddef.h>

// E=8, B=16, T=512, DIN=256, D=256; M = B*T = 8192 rows per ensemble member.
// Stage1: u = x @ W_in[m], v=tanh(u0), f=sig(u1)*(1-rs)  -> scan1 -> v4
// Stage2: u = v4 @ W_mid[m], gates f,i,o,z               -> scan2 -> g = h*o
// Stage3: out = g @ W_out + b_out
//
// Persistent weight-stationary GEMM: grid=256 (1 block/CU), B-panel (128 cols
// x K=256 = 64KB) resident in LDS, A streamed in 128x128k chunks (2x32KB dbuf,
// global_load_lds, counted vmcnt). bf16 MFMA 16x16x32, f32 accum.

typedef __bf16 bf16x8 __attribute__((ext_vector_type(8)));
typedef __bf16 bf16x4 __attribute__((ext_vector_type(4)));
typedef float  f32x4  __attribute__((ext_vector_type(4)));
typedef unsigned int u32x2 __attribute__((ext_vector_type(2)));

#define E_ 8
#define M_ 8192
#define K_ 256

__device__ __forceinline__ float sigm_f(float x) { return 1.0f / (1.0f + __expf(-x)); }
__device__ __forceinline__ float tanh_f(float x) { return 1.0f - 2.0f / (1.0f + __expf(2.0f * x)); }

__device__ __forceinline__ void g2lds16(const void* g, void* l) {
    __builtin_amdgcn_global_load_lds((const __attribute__((address_space(1))) void*)g,
                                     (__attribute__((address_space(3))) void*)l, 16, 0, 0);
}

// ---------------- convert x to bf16 ----------------
__global__ __launch_bounds__(256) void convx_k(const float* __restrict__ x, __bf16* __restrict__ xb) {
    int i = blockIdx.x * 256 + threadIdx.x;
    float4 v = ((const float4*)x)[i];
    bf16x4 o;
    o[0] = (__bf16)v.x; o[1] = (__bf16)v.y; o[2] = (__bf16)v.z; o[3] = (__bf16)v.w;
    ((bf16x4*)xb)[i] = o;
}

// ---------------- transpose+convert weights: src [GE][K][D] f32 -> dst [E][NG*256][K] bf16 ----
__global__ __launch_bounds__(256) void transw_k(const float* __restrict__ src, __bf16* __restrict__ dst, int NG) {
    int ge = blockIdx.z;
    int g = ge >> 3, e = ge & 7;
    int k0 = blockIdx.x * 64, d0 = blockIdx.y * 64;
    __shared__ float tile[64][65];
    int t = threadIdx.x;
#pragma unroll
    for (int j = 0; j < 16; ++j) {
        int lin = j * 256 + t;
        int r = lin >> 6, c = lin & 63;
        tile[r][c] = src[((size_t)(ge * 256 + k0 + r)) * 256 + d0 + c];
    }
    __syncthreads();
#pragma unroll
    for (int j = 0; j < 16; ++j) {
        int lin = j * 256 + t;
        int r = lin >> 6, c = lin & 63;
        dst[((size_t)((e * NG + g) * 256 + d0 + r)) * 256 + k0 + c] = (__bf16)tile[c][r];
    }
}

// ---------------- persistent GEMM ----------------
// A [E][M][K] bf16, Wt [E][NG*256][K] bf16.
// MODE 0: NG=2 (g0 tanh, g1 sig*(1-rs)); MODE 1: NG=4 (g0 sig*(1-rs), g1 sig, g2 sig, g3 tanh);
// MODE 2: NG=1 linear+bias -> f32.
template <int MODE, int NG, int NMT>
__global__ __launch_bounds__(256, 1) void gemm_k(const __bf16* __restrict__ A,
                                                 const __bf16* __restrict__ Wt,
                                                 const float* __restrict__ bias,
                                                 const float* __restrict__ rs,
                                                 __bf16* __restrict__ gout,
                                                 float* __restrict__ fout) {
    constexpr int NT = NG * 2;            // n-panels of 128
    const int tid = threadIdx.x;
    const int bid = blockIdx.x;           // 256 blocks exactly
    const int e = bid & 7;                // same e -> same XCD (L2 locality)
    const int r = bid >> 3;               // 0..31
    const int nt = r % NT;
    const int ms = r / NT;                // 0..(32/NT)-1
    const int mt0 = ms * NMT;
    const int lane = tid & 63, wid = tid >> 6;
    const int wr = wid >> 1, wc = wid & 1;

    __shared__ __align__(16) __bf16 Bs[32768];      // 128 cols x 256 k  (64 KB, resident)
    __shared__ __align__(16) __bf16 As[2][16384];   // 2 x (128 rows x 128 k) (2x32 KB)

    const size_t Bbase = ((size_t)e * (NG * 256) + nt * 128) * K_;
    const size_t Ab = (size_t)e * M_ * K_;

    // ---- prologue: stage B panel (16 loads) + first A chunk (8 loads) ----
#pragma unroll
    for (int it = 0; it < 16; ++it) {
        int P = it * 256 + tid;           // 16B granule, 0..4095
        int col = P >> 5, gl = P & 31;
        int gs = gl ^ (col & 7);
        g2lds16(Wt + Bbase + (size_t)col * K_ + gs * 8, &Bs[P * 16 / 2]);
    }
    auto stageA = [&](int mt, int kc, int buf) {
#pragma unroll
        for (int it = 0; it < 8; ++it) {
            int P = it * 256 + tid;       // 0..2047
            int row = P >> 4, gl = P & 15;
            int gs = gl ^ (row & 7);
            g2lds16(A + Ab + (size_t)(mt * 128 + row) * K_ + kc * 128 + gs * 8, &As[buf][P * 8]);
        }
    };
    stageA(mt0, 0, 0);
    asm volatile("s_waitcnt vmcnt(0)" ::: "memory");
    __builtin_amdgcn_s_barrier();
    __builtin_amdgcn_sched_barrier(0);

    f32x4 acc[4][4] = {};

    auto compute = [&](int buf, int kc) {
#pragma unroll
        for (int ks = 0; ks < 4; ++ks) {
            bf16x8 af[4], bfr[4];
#pragma unroll
            for (int i = 0; i < 4; ++i) {
                int ar = wr * 64 + i * 16 + (lane & 15);
                int ag = (ks * 4 + (lane >> 4)) ^ (ar & 7);
                af[i] = *(const bf16x8*)&As[buf][ar * 128 + ag * 8];
                int bc = wc * 64 + i * 16 + (lane & 15);
                int bg = (kc * 16 + ks * 4 + (lane >> 4)) ^ (bc & 7);
                bfr[i] = *(const bf16x8*)&Bs[bc * 256 + bg * 8];
            }
#pragma unroll
            for (int i = 0; i < 4; ++i)
#pragma unroll
                for (int j = 0; j < 4; ++j)
                    acc[i][j] = __builtin_amdgcn_mfma_f32_16x16x32_bf16(bfr[j], af[i], acc[i][j], 0, 0, 0);
        }
    };

    for (int t = 0; t < NMT; ++t) {
        const int mt = mt0 + t;
        // ---- phase A (kc=0 in As[0]); prefetch kc=1 ----
        stageA(mt, 1, 1);
        asm volatile("s_waitcnt vmcnt(24)" ::: "memory");   // chunk(mt,0) ready; stores may linger
        __builtin_amdgcn_s_barrier();
        __builtin_amdgcn_sched_barrier(0);
        compute(0, 0);
        asm volatile("s_waitcnt lgkmcnt(0)" ::: "memory");
        __builtin_amdgcn_s_barrier();
        __builtin_amdgcn_sched_barrier(0);
        // ---- phase B (kc=1 in As[1]); prefetch next mt kc=0 ----
        if (t + 1 < NMT) stageA(mt + 1, 0, 0);
        asm volatile("s_waitcnt vmcnt(8)" ::: "memory");    // chunk(mt,1) ready
        __builtin_amdgcn_s_barrier();
        __builtin_amdgcn_sched_barrier(0);
        compute(1, 1);
        asm volatile("s_waitcnt lgkmcnt(0)" ::: "memory");
        __builtin_amdgcn_sched_barrier(0);

        // ---- epilogue for this mt (no LDS; stores fire-and-forget) ----
        {
            const int mlo = mt * 128 + wr * 64 + (lane & 15);
            float rsv[4];
            if (MODE != 2) {
#pragma unroll
                for (int i = 0; i < 4; ++i) rsv[i] = 1.0f - rs[mlo + i * 16];
            }
#pragma unroll
            for (int j = 0; j < 4; ++j) {
                int nb = nt * 128 + wc * 64 + j * 16 + ((lane >> 4) << 2);
                int g = nb >> 8, d = nb & 255;
                f32x4 bv = *(const f32x4*)&bias[(g * E_ + e) * 256 + d];
#pragma unroll
                for (int i = 0; i < 4; ++i) {
                    int m = mlo + i * 16;
                    if (MODE == 2) {
                        f32x4 o = acc[i][j] + bv;
                        *(f32x4*)&fout[((size_t)e * M_ + m) * 256 + d] = o;
                    } else {
                        bf16x4 pk;
#pragma unroll
                        for (int q = 0; q < 4; ++q) {
                            float u = acc[i][j][q] + bv[q];
                            bool is_tanh = (MODE == 0) ? (g == 0) : (g == 3);
                            bool gated   = (MODE == 0) ? (g == 1) : (g == 0);
                            float a = is_tanh ? tanh_f(u) : sigm_f(u);
                            if (gated) a *= rsv[i];
                            pk[q] = (__bf16)a;
                        }
                        *(u32x2*)&gout[(((size_t)g * E_ + e) * M_ + m) * 256 + d] = __builtin_bit_cast(u32x2, pk);
                    }
                    acc[i][j] = f32x4{};
                }
            }
        }
        __builtin_amdgcn_s_barrier();
        __builtin_amdgcn_sched_barrier(0);
    }
}

// ---------------- scan 1: h = f*h + (1-f)*v ----
__global__ __launch_bounds__(64) void scan1_k(const __bf16* __restrict__ V, const __bf16* __restrict__ F,
                                              const float* __restrict__ hidden,
                                              __bf16* __restrict__ v4b, float* __restrict__ hidout) {
    int gid = blockIdx.x * 64 + threadIdx.x;    // 0..32767
    int n = gid >> 8, d = gid & 255;
    float h = hidden[n * 512 + d];
    size_t base = (size_t)n * 512 * 256 + d;
#pragma unroll 1
    for (int tb = 0; tb < 512; tb += 16) {
        float fv[16], bv[16];
#pragma unroll
        for (int u = 0; u < 16; ++u) {
            size_t idx = base + (size_t)(tb + u) * 256;
            float f = (float)F[idx];
            float v = (float)V[idx];
            fv[u] = f; bv[u] = (1.0f - f) * v;
        }
#pragma unroll
        for (int u = 0; u < 16; ++u) {
            h = __builtin_fmaf(fv[u], h, bv[u]);
            v4b[base + (size_t)(tb + u) * 256] = (__bf16)h;
        }
    }
    hidout[n * 512 + d] = h;
}

// ---------------- scan 2: h = f*h + (1-f)*(i*z); out = h*o ----
__global__ __launch_bounds__(64) void scan2_k(const __bf16* __restrict__ Fg, const __bf16* __restrict__ Ig,
                                              const __bf16* __restrict__ Og, const __bf16* __restrict__ Zg,
                                              const float* __restrict__ hidden,
                                              __bf16* __restrict__ G, float* __restrict__ hidout) {
    int gid = blockIdx.x * 64 + threadIdx.x;
    int n = gid >> 8, d = gid & 255;
    float h = hidden[n * 512 + 256 + d];
    size_t base = (size_t)n * 512 * 256 + d;
#pragma unroll 1
    for (int tb = 0; tb < 512; tb += 16) {
        float fv[16], bv[16], ov[16];
#pragma unroll
        for (int u = 0; u < 16; ++u) {
            size_t idx = base + (size_t)(tb + u) * 256;
            float f = (float)Fg[idx], iv = (float)Ig[idx], o = (float)Og[idx], z = (float)Zg[idx];
            fv[u] = f; bv[u] = (1.0f - f) * (iv * z); ov[u] = o;
        }
#pragma unroll
        for (int u = 0; u < 16; ++u) {
            h = __builtin_fmaf(fv[u], h, bv[u]);
            size_t idx = base + (size_t)(tb + u) * 256;
            G[idx] = (__bf16)(h * ov[u]);
        }
    }
    hidout[n * 512 + 256 + d] = h;
}

extern "C" void kernel_launch(void* const* d_in, const int* in_sizes, int n_in,
                              void* d_out, int out_size, void* d_ws, size_t ws_size,
                              hipStream_t stream) {
    const float* x      = (const float*)d_in[0];
    const float* hidden = (const float*)d_in[1];
    const float* rs     = (const float*)d_in[2];
    const float* W_in   = (const float*)d_in[3];
    const float* b_in   = (const float*)d_in[4];
    const float* W_mid  = (const float*)d_in[5];
    const float* b_mid  = (const float*)d_in[6];
    const float* W_out  = (const float*)d_in[7];
    const float* b_out  = (const float*)d_in[8];
    float* out = (float*)d_out;

    char* ws = (char*)d_ws;
    const size_t MiB = (size_t)1 << 20;
    __bf16* Wt1 = (__bf16*)(ws + 0);               // 2 MiB
    __bf16* Wt2 = (__bf16*)(ws + 2 * MiB);         // 4 MiB
    __bf16* Wt3 = (__bf16*)(ws + 6 * MiB);         // 1 MiB
    __bf16* v4b = (__bf16*)(ws + 8 * MiB);         // 32 MiB; reused as G after gemm2
    __bf16* xb  = (__bf16*)(ws + 40 * MiB);        // 32 MiB
    __bf16* g1  = (__bf16*)(ws + 72 * MiB);        // 64 MiB  [2][E][M][D]
    __bf16* g2  = (__bf16*)(ws + 40 * MiB);        // 128 MiB [4][E][M][D], overlays xb+g1
    const size_t S1 = (size_t)E_ * M_ * 256;

    float* hidout = out + (size_t)E_ * M_ * 256;

    convx_k<<<16384, 256, 0, stream>>>(x, xb);
    transw_k<<<dim3(4, 4, 16), 256, 0, stream>>>(W_in, Wt1, 2);
    transw_k<<<dim3(4, 4, 32), 256, 0, stream>>>(W_mid, Wt2, 4);
    transw_k<<<dim3(4, 4, 8), 256, 0, stream>>>(W_out, Wt3, 1);

    // grid = 256 blocks (1/CU) for all three GEMMs
    gemm_k<0, 2, 8><<<256, 256, 0, stream>>>(xb, Wt1, b_in, rs, g1, nullptr);
    scan1_k<<<512, 64, 0, stream>>>(g1, g1 + S1, hidden, v4b, hidout);
    gemm_k<1, 4, 16><<<256, 256, 0, stream>>>(v4b, Wt2, b_mid, rs, g2, nullptr);
    scan2_k<<<512, 64, 0, stream>>>(g2, g2 + S1, g2 + 2 * S1, g2 + 3 * S1, hidden, v4b, hidout);
    gemm_k<2, 1, 4><<<256, 256, 0, stream>>>(v4b, Wt3, b_out, nullptr, nullptr, out);
}

// Round 4
// 249.584 us; speedup vs baseline: 1.2526x; 1.1204x over previous
//
#include <hip/hip_runtime.h>
#include <hip/hip_bf16.h>
#include <stdint.h>
#include <stddef.h>

// E=8, B=16, T=512, DIN=256, D=256; M = B*T = 8192 rows per ensemble member.
// Stage1: u = x @ W_in[m], v=tanh(u0), f=sig(u1)*(1-rs)  -> scan1 -> v4
// Stage2: u = v4 @ W_mid[m], gates f,i,o,z               -> scan2 -> g = h*o
// Stage3: out = g @ W_out + b_out
//
// r4 GEMM: persistent, B(weights) in REGISTERS (128 VGPR/lane), A streamed
// through an 8-deep LDS chunk pipeline (8x8KB), zero-VALU inner-loop LDS
// addressing (base + compile-time offsets), bias/rs preloaded.

typedef __bf16 bf16x8 __attribute__((ext_vector_type(8)));
typedef __bf16 bf16x4 __attribute__((ext_vector_type(4)));
typedef __bf16 bf16x2 __attribute__((ext_vector_type(2)));
typedef float  f32x4  __attribute__((ext_vector_type(4)));
typedef unsigned int u32x2 __attribute__((ext_vector_type(2)));

#define E_ 8
#define M_ 8192
#define K_ 256

__device__ __forceinline__ float sigm_f(float x) { return 1.0f / (1.0f + __expf(-x)); }
__device__ __forceinline__ float tanh_f(float x) { return 1.0f - 2.0f / (1.0f + __expf(2.0f * x)); }

__device__ __forceinline__ void g2lds16(const void* g, void* l) {
    __builtin_amdgcn_global_load_lds((const __attribute__((address_space(1))) void*)g,
                                     (__attribute__((address_space(3))) void*)l, 16, 0, 0);
}

// ---------------- convert x to bf16 ----------------
__global__ __launch_bounds__(256) void convx_k(const float* __restrict__ x, __bf16* __restrict__ xb) {
    int i = blockIdx.x * 256 + threadIdx.x;
    float4 v = ((const float4*)x)[i];
    bf16x4 o;
    o[0] = (__bf16)v.x; o[1] = (__bf16)v.y; o[2] = (__bf16)v.z; o[3] = (__bf16)v.w;
    ((bf16x4*)xb)[i] = o;
}

// ---------------- rs -> tile-layout (1-rs) table: rsp[mt*128 + half*64 + r15*4 + i] ----
__global__ __launch_bounds__(256) void rsprep_k(const float* __restrict__ rs, float* __restrict__ rsp) {
    int idx = blockIdx.x * 256 + threadIdx.x;      // 0..8191
    int mt = idx >> 7, rem = idx & 127;
    int half = rem >> 6, r15 = (rem >> 2) & 15, i = rem & 3;
    rsp[idx] = 1.0f - rs[mt * 128 + half * 64 + i * 16 + r15];
}

// ---------------- transpose+convert weights: src [GE][K][D] f32 -> dst [E][NG*256][K] bf16 ----
__global__ __launch_bounds__(256) void transw_k(const float* __restrict__ src, __bf16* __restrict__ dst, int NG) {
    int ge = blockIdx.z;
    int g = ge >> 3, e = ge & 7;
    int k0 = blockIdx.x * 64, d0 = blockIdx.y * 64;
    __shared__ float tile[64][65];
    int t = threadIdx.x;
#pragma unroll
    for (int j = 0; j < 16; ++j) {
        int lin = j * 256 + t;
        int r = lin >> 6, c = lin & 63;
        tile[r][c] = src[((size_t)(ge * 256 + k0 + r)) * 256 + d0 + c];
    }
    __syncthreads();
#pragma unroll
    for (int j = 0; j < 16; ++j) {
        int lin = j * 256 + t;
        int r = lin >> 6, c = lin & 63;
        dst[((size_t)((e * NG + g) * 256 + d0 + r)) * 256 + k0 + c] = (__bf16)tile[c][r];
    }
}

// ---------------- persistent GEMM, B-in-registers ----------------
// A [E][M][K] bf16, Wt [E][NG*256][K] bf16.
// MODE 0: NG=2 (g0 tanh, g1 sig*(1-rs)); MODE 1: NG=4 (g0 sig*(1-rs), g1/g2 sig, g3 tanh);
// MODE 2: NG=1 linear+bias -> f32.
template <int MODE, int NG, int NMT>
__global__ __launch_bounds__(256, 2) void gemm_k(const __bf16* __restrict__ A,
                                                 const __bf16* __restrict__ Wt,
                                                 const float* __restrict__ bias,
                                                 const float* __restrict__ rsp,
                                                 __bf16* __restrict__ gout,
                                                 float* __restrict__ fout) {
    constexpr int NT = NG * 2;                 // n-panels of 128
    constexpr int NC = NMT * 8;                // k32-chunks streamed per block
    const int tid = threadIdx.x;
    const int bid = blockIdx.x;                // 512 blocks
    const int e = bid & 7;
    const int r = bid >> 3;                    // 0..63
    const int nt = r % NT;
    const int ms = r / NT;
    const int mt0 = ms * NMT;
    const int lane = tid & 63, wid = tid >> 6;
    const int wr = wid >> 1, wc = wid & 1;     // 2x2 wave grid over 128x128 tile

    __shared__ __align__(16) __bf16 As[8][4096];   // 8 bufs x (128 rows x 32 k) = 64 KB

    // ---- B panel into registers: per lane 4 j-tiles x 8 k32-chunks x bf16x8 ----
    const size_t Bbase = ((size_t)e * (NG * 256) + nt * 128) * K_;
    bf16x8 Breg[4][8];
    {
        const __bf16* bp = Wt + Bbase + (size_t)(wc * 64 + (lane & 15)) * K_ + (lane >> 4) * 8;
#pragma unroll
        for (int j = 0; j < 4; ++j)
#pragma unroll
            for (int kc = 0; kc < 8; ++kc)
                Breg[j][kc] = *(const bf16x8*)(bp + j * 16 * K_ + kc * 32);
    }
    // ---- bias preload (mt-invariant) ----
    f32x4 bias_v[4];
#pragma unroll
    for (int j = 0; j < 4; ++j) {
        int nb = nt * 128 + wc * 64 + j * 16 + ((lane >> 4) << 2);
        int g = nb >> 8, d = nb & 255;
        bias_v[j] = *(const f32x4*)&bias[(g * E_ + e) * 256 + d];
    }

    // ---- per-thread staging source bases (granules P0=tid, P1=256+tid) ----
    const size_t Ae = ((size_t)e * M_ + (size_t)mt0 * 128) * K_;
    const int P0 = tid, P1 = 256 + tid;
    const int r0 = P0 >> 2, g0 = (P0 & 3) ^ ((r0 >> 1) & 3);
    const int r1 = P1 >> 2, g1 = (P1 & 3) ^ ((r1 >> 1) & 3);
    const __bf16* sA0 = A + Ae + (size_t)r0 * K_ + g0 * 8;
    const __bf16* sA1 = A + Ae + (size_t)r1 * K_ + g1 * 8;
    __bf16* const ld0 = &As[0][0] + P0 * 8;
    __bf16* const ld1 = &As[0][0] + P1 * 8;

    auto stage = [&](int c) {                  // 2 global_load_lds per thread
        int off = (c >> 3) * (128 * K_) + (c & 7) * 32;
        int lo = (c & 7) * 4096;
        g2lds16(sA0 + off, ld0 + lo);
        g2lds16(sA1 + off, ld1 + lo);
    };

    // ---- A-fragment LDS base (lane-only; buf/i via immediate offsets) ----
    const __bf16* abase = &As[0][0]
        + (wr * 64 + (lane & 15)) * 32
        + (((lane >> 4) ^ (((lane & 15) >> 1) & 3)) * 8);

    // ---- prologue: issue chunks 0..6 ----
#pragma unroll
    for (int c = 0; c < 7; ++c) stage(c);

    f32x4 acc[4][4] = {};

    for (int t = 0; t < NMT; ++t) {
        f32x4 rsv;
        if (MODE != 2) rsv = *(const f32x4*)&rsp[(mt0 + t) * 128 + wr * 64 + (lane & 15) * 4];
#pragma unroll
        for (int s = 0; s < 8; ++s) {
            const int c = t * 8 + s;
            asm volatile("s_waitcnt vmcnt(12)" ::: "memory");   // chunk c complete
            __builtin_amdgcn_s_barrier();
            {   // prefetch chunk c+7 (clamped; duplicate re-issue of last chunk is benign)
                int cn = c + 7; if (cn > NC - 1) cn = NC - 1;
                stage(cn);
            }
            bf16x8 af[4];
#pragma unroll
            for (int i = 0; i < 4; ++i)
                af[i] = *(const bf16x8*)(abase + s * 4096 + i * 512);
#pragma unroll
            for (int i = 0; i < 4; ++i)
#pragma unroll
                for (int j = 0; j < 4; ++j)
                    acc[i][j] = __builtin_amdgcn_mfma_f32_16x16x32_bf16(Breg[j][s], af[i], acc[i][j], 0, 0, 0);
        }

        // ---- epilogue for mt = mt0+t ----
        const int mlo = (mt0 + t) * 128 + wr * 64 + (lane & 15);
#pragma unroll
        for (int j = 0; j < 4; ++j) {
            int nb = nt * 128 + wc * 64 + j * 16 + ((lane >> 4) << 2);
            int g = nb >> 8, d = nb & 255;
#pragma unroll
            for (int i = 0; i < 4; ++i) {
                int m = mlo + i * 16;
                if (MODE == 2) {
                    f32x4 o = acc[i][j] + bias_v[j];
                    *(f32x4*)&fout[((size_t)e * M_ + m) * 256 + d] = o;
                } else {
                    bf16x4 pk;
#pragma unroll
                    for (int q = 0; q < 4; ++q) {
                        float u = acc[i][j][q] + bias_v[j][q];
                        bool is_tanh = (MODE == 0) ? (g == 0) : (g == 3);
                        bool gated   = (MODE == 0) ? (g == 1) : (g == 0);
                        float a = is_tanh ? tanh_f(u) : sigm_f(u);
                        if (gated) a *= rsv[i];
                        pk[q] = (__bf16)a;
                    }
                    *(u32x2*)&gout[(((size_t)g * E_ + e) * M_ + m) * 256 + d] = __builtin_bit_cast(u32x2, pk);
                }
                acc[i][j] = f32x4{};
            }
        }
    }
}

// ---------------- scan 1: h = f*h + (1-f)*v ----
__global__ __launch_bounds__(64) void scan1_k(const __bf16* __restrict__ V, const __bf16* __restrict__ F,
                                              const float* __restrict__ hidden,
                                              __bf16* __restrict__ v4b, float* __restrict__ hidout) {
    int gid = blockIdx.x * 64 + threadIdx.x;    // 0..32767
    int n = gid >> 8, d = gid & 255;
    float h = hidden[n * 512 + d];
    size_t base = (size_t)n * 512 * 256 + d;
#pragma unroll 1
    for (int tb = 0; tb < 512; tb += 16) {
        float fv[16], bv[16];
#pragma unroll
        for (int u = 0; u < 16; ++u) {
            size_t idx = base + (size_t)(tb + u) * 256;
            float f = (float)F[idx];
            float v = (float)V[idx];
            fv[u] = f; bv[u] = (1.0f - f) * v;
        }
#pragma unroll
        for (int u = 0; u < 16; ++u) {
            h = __builtin_fmaf(fv[u], h, bv[u]);
            v4b[base + (size_t)(tb + u) * 256] = (__bf16)h;
        }
    }
    hidout[n * 512 + d] = h;
}

// ---------------- scan 2: h = f*h + (1-f)*(i*z); out = h*o ----
__global__ __launch_bounds__(64) void scan2_k(const __bf16* __restrict__ Fg, const __bf16* __restrict__ Ig,
                                              const __bf16* __restrict__ Og, const __bf16* __restrict__ Zg,
                                              const float* __restrict__ hidden,
                                              __bf16* __restrict__ G, float* __restrict__ hidout) {
    int gid = blockIdx.x * 64 + threadIdx.x;
    int n = gid >> 8, d = gid & 255;
    float h = hidden[n * 512 + 256 + d];
    size_t base = (size_t)n * 512 * 256 + d;
#pragma unroll 1
    for (int tb = 0; tb < 512; tb += 16) {
        float fv[16], bv[16], ov[16];
#pragma unroll
        for (int u = 0; u < 16; ++u) {
            size_t idx = base + (size_t)(tb + u) * 256;
            float f = (float)Fg[idx], iv = (float)Ig[idx], o = (float)Og[idx], z = (float)Zg[idx];
            fv[u] = f; bv[u] = (1.0f - f) * (iv * z); ov[u] = o;
        }
#pragma unroll
        for (int u = 0; u < 16; ++u) {
            h = __builtin_fmaf(fv[u], h, bv[u]);
            size_t idx = base + (size_t)(tb + u) * 256;
            G[idx] = (__bf16)(h * ov[u]);
        }
    }
    hidout[n * 512 + 256 + d] = h;
}

extern "C" void kernel_launch(void* const* d_in, const int* in_sizes, int n_in,
                              void* d_out, int out_size, void* d_ws, size_t ws_size,
                              hipStream_t stream) {
    const float* x      = (const float*)d_in[0];
    const float* hidden = (const float*)d_in[1];
    const float* rs     = (const float*)d_in[2];
    const float* W_in   = (const float*)d_in[3];
    const float* b_in   = (const float*)d_in[4];
    const float* W_mid  = (const float*)d_in[5];
    const float* b_mid  = (const float*)d_in[6];
    const float* W_out  = (const float*)d_in[7];
    const float* b_out  = (const float*)d_in[8];
    float* out = (float*)d_out;

    char* ws = (char*)d_ws;
    const size_t MiB = (size_t)1 << 20;
    __bf16* Wt1 = (__bf16*)(ws + 0);               // 2 MiB
    __bf16* Wt2 = (__bf16*)(ws + 2 * MiB);         // 4 MiB
    __bf16* Wt3 = (__bf16*)(ws + 6 * MiB);         // 1 MiB
    float*  rsp = (float*)(ws + 7 * MiB);          // 32 KiB tile-layout (1-rs)
    __bf16* v4b = (__bf16*)(ws + 8 * MiB);         // 32 MiB; reused as G after gemm2
    __bf16* xb  = (__bf16*)(ws + 40 * MiB);        // 32 MiB
    __bf16* g1  = (__bf16*)(ws + 72 * MiB);        // 64 MiB  [2][E][M][D]
    __bf16* g2  = (__bf16*)(ws + 40 * MiB);        // 128 MiB [4][E][M][D], overlays xb+g1
    const size_t S1 = (size_t)E_ * M_ * 256;

    float* hidout = out + (size_t)E_ * M_ * 256;

    convx_k<<<16384, 256, 0, stream>>>(x, xb);
    rsprep_k<<<32, 256, 0, stream>>>(rs, rsp);
    transw_k<<<dim3(4, 4, 16), 256, 0, stream>>>(W_in, Wt1, 2);
    transw_k<<<dim3(4, 4, 32), 256, 0, stream>>>(W_mid, Wt2, 4);
    transw_k<<<dim3(4, 4, 8), 256, 0, stream>>>(W_out, Wt3, 1);

    // grid = 512 blocks (2/CU) for all three GEMMs
    gemm_k<0, 2, 4><<<512, 256, 0, stream>>>(xb, Wt1, b_in, rsp, g1, nullptr);
    scan1_k<<<512, 64, 0, stream>>>(g1, g1 + S1, hidden, v4b, hidout);
    gemm_k<1, 4, 8><<<512, 256, 0, stream>>>(v4b, Wt2, b_mid, rsp, g2, nullptr);
    scan2_k<<<512, 64, 0, stream>>>(g2, g2 + S1, g2 + 2 * S1, g2 + 3 * S1, hidden, v4b, hidout);
    gemm_k<2, 1, 2><<<512, 256, 0, stream>>>(v4b, Wt3, b_out, nullptr, nullptr, out);
}